// Round 6
// baseline (857.457 us; speedup 1.0000x reference)
//
#include <hip/hip_runtime.h>

typedef __bf16 bf16;
typedef bf16 bf16x8 __attribute__((ext_vector_type(8)));
typedef float f32x4 __attribute__((ext_vector_type(4)));

#define NUM_MOLS 2000
#define APM 50
#define NA (NUM_MOLS*APM+1)      // 100001
#define NB (2*NUM_MOLS*APM+1)    // 200001
#define MAX_NB 6
#define AF 133
#define BFD 147
#define H 300
#define HP 320
#define KIP 192                  // padded BOND_FDIM (3 x 64)
#define KO 448                   // padded concat dim: 133 + 3 pad + 300 + 12 pad
#define AOFF 136                 // a_message column offset inside cat
#define BM 64

typedef const __attribute__((address_space(1))) void gvoid_t;
typedef __attribute__((address_space(3))) void lvoid_t;
__device__ __forceinline__ void gload16(const void* g, void* l) {
    __builtin_amdgcn_global_load_lds((gvoid_t*)g, (lvoid_t*)l, 16, 0, 0);
}

// fragment-image decode: elem index e of a [K/64][40 frags][64 lanes][8] tensor
// frag layout (B): frag = wn*10 + n*2 + kh ; row = wn*80+n*16+(lane&15),
// col = s*64 + kh*32 + (lane>>4)*8 + j
__device__ __forceinline__ void frag_decode(int e, int& row, int& col, int& j){
    int s = e / 20480;
    int r = e - s*20480;
    int q = r >> 3; j = r & 7;
    int frag = q >> 6, lane = q & 63;
    int wn = frag / 10, rem = frag - wn*10;
    int n = rem >> 1, kh = rem & 1;
    row = wn*80 + n*16 + (lane & 15);
    col = s*64 + kh*32 + ((lane >> 4) << 3) + j;
}

// ---- weight prep: pad + transpose + fragment-order (Btg = LDS image per 64-step) ----
// W=0: W_i [BFD][H]   K=KIP ; W=1: W_h [H][H] K=HP ; W=2: W_o [AF+H][H] K=KO
template<int W, int K>
__global__ void k_prep(const float* __restrict__ src, bf16* __restrict__ dst){
    int e = blockIdx.x*256 + threadIdx.x;
    if (e >= HP*K) return;
    int row, col, j; frag_decode(e, row, col, j);
    float v = 0.f;
    if (row < H) {
        if constexpr (W == 0)      { if (col < BFD) v = src[col*H + row]; }
        else if constexpr (W == 1) { if (col < H)   v = src[col*H + row]; }
        else { if (col < AF) v = src[col*H + row];
               else if (col >= AOFF && col < AOFF+H) v = src[(col-AOFF+AF)*H + row]; }
    }
    dst[e] = (bf16)v;
}

// cat [NA][KO]: cols 0..135 <- f_atoms (133 real + 3 zero), cols 440..447 <- 0
__global__ void k_init_cat(const float* __restrict__ fa, bf16* __restrict__ cat){
    long u = (long)blockIdx.x*256 + threadIdx.x; if (u >= (long)NA*18) return;
    int c = (int)(u % 18); long a = u / 18;
    bf16x8 v;
    if (c < 17) {
        int c0 = c*8;
        #pragma unroll
        for (int j=0;j<8;j++){
            int col = c0 + j;
            float f = (col < AF) ? fa[a*AF + col] : 0.f;
            v[j] = (bf16)f;
        }
        *(bf16x8*)(cat + a*KO + c0) = v;
    } else {
        #pragma unroll
        for (int j=0;j<8;j++) v[j] = (bf16)0.f;
        *(bf16x8*)(cat + a*KO + 440) = v;
    }
}

// ---- gather: out[a] = sum_k w_bonds[a2b[a,k]] * relu(msgraw[a2b[a,k]]) ----
__global__ void k_gather_amsg(const bf16* __restrict__ msg, const int* __restrict__ a2b,
                              const float* __restrict__ w_bonds,
                              bf16* __restrict__ out, int out_stride, int col_off, int nchunks){
    long u = (long)blockIdx.x*256 + threadIdx.x;
    if (u >= (long)NA*nchunks) return;
    int c = (int)(u % nchunks); long a = u / nchunks;
    int c0 = c*8;
    float acc[8] = {0,0,0,0,0,0,0,0};
    #pragma unroll
    for (int k=0;k<MAX_NB;k++){
        int b = a2b[a*MAX_NB + k];
        float w = w_bonds[b];
        bf16x8 m = *(const bf16x8*)(msg + (long)b*HP + c0);
        #pragma unroll
        for (int j=0;j<8;j++) acc[j] += w * fmaxf((float)m[j], 0.f);
    }
    bf16x8 o;
    #pragma unroll
    for (int j=0;j<8;j++) o[j] = (bf16)acc[j];
    *(bf16x8*)(out + (long)a*out_stride + col_off + c0) = o;
}

// ---- MFMA GEMM: BM=64 x BN=320(full), full-K A-burst, B async via global_load_lds ----
// MODE 0: A = f_bonds fp32 [M][147] convert+pad (reg-staged)
// MODE 1: A[b] = amsg[b2a[b]] - relu(msgsrc[b2revb[b]])*w_b (reg-staged, fused)
// MODE 2: A = cat bf16 [M][KO] (global_load_lds direct); +bias +relu
// Btg: fragment-ordered weight image, (K/64) steps x 40960 B. out: [M][HP] bf16.
template<int MODE, int K>
__global__ __launch_bounds__(512, 4)
void k_gemm(const void* __restrict__ Asrc, const bf16* __restrict__ msgsrc,
            const int* __restrict__ b2a, const int* __restrict__ b2revb,
            const float* __restrict__ w_bonds,
            const bf16* __restrict__ Btg, int M,
            const bf16* __restrict__ add, const float* __restrict__ bias,
            bf16* __restrict__ out)
{
    constexpr int NKB = K/32, NSTEP = K/64, NJ = K/64;
    __shared__ bf16 As[64*K];       // fragment-ordered, exact
    __shared__ bf16 Bs[20480];      // one 64-col step, fragment-ordered
    const int t = threadIdx.x, lane = t & 63, wv = t >> 6;
    const int row0 = blockIdx.x * BM;

    // per-chunk A geometry: chunk c = i*512 + t -> frag = i*8 + wv, lane fixed
    int acol[NJ]; int agrow[NJ];
    #pragma unroll
    for (int i = 0; i < NJ; i++) {
        int frag = i*8 + wv;
        int rg = frag / NKB, kb = frag - rg*NKB;
        int grow = row0 + rg*16 + (lane & 15);
        if (grow >= M) grow = M - 1;
        agrow[i] = grow;
        acol[i]  = kb*32 + ((lane >> 4) << 3);
    }

    bf16x8 ra[MODE==1?NJ:1], rm[MODE==1?NJ:1];
    float  wbv[MODE==1?NJ:1];
    float  f8[MODE==0?NJ:1][8];

    // ---------- A burst: ALL loads issued up-front ----------
    if constexpr (MODE == 0) {
        const float* fb = (const float*)Asrc;
        #pragma unroll
        for (int i = 0; i < NJ; i++)
            #pragma unroll
            for (int j = 0; j < 8; j++) {
                int k = acol[i] + j;
                f8[i][j] = (k < BFD) ? fb[(long)agrow[i]*BFD + k] : 0.f;
            }
    } else if constexpr (MODE == 1) {
        const bf16* am = (const bf16*)Asrc;
        #pragma unroll
        for (int i = 0; i < NJ; i++) {
            int ia = b2a[agrow[i]], ir = b2revb[agrow[i]];
            wbv[i] = w_bonds[agrow[i]];
            ra[i] = *(const bf16x8*)(am     + (long)ia*HP + acol[i]);
            rm[i] = *(const bf16x8*)(msgsrc + (long)ir*HP + acol[i]);
        }
    } else {
        const bf16* cat = (const bf16*)Asrc;
        #pragma unroll
        for (int i = 0; i < NJ; i++)
            gload16(cat + (long)agrow[i]*KO + acol[i], As + ((long)i*512 + (t & ~63))*8);
    }

    // ---------- B step 0 (async DMA, no VGPRs) ----------
    #pragma unroll
    for (int i = 0; i < 5; i++)
        gload16(Btg + (long)(i*512 + t)*8, Bs + ((long)i*512 + (t & ~63))*8);

    // ---------- commit A to LDS (consecutive 16B per lane: conflict-free) ----------
    if constexpr (MODE == 0) {
        #pragma unroll
        for (int i = 0; i < NJ; i++) {
            bf16x8 av;
            #pragma unroll
            for (int j = 0; j < 8; j++) av[j] = (bf16)f8[i][j];
            *(bf16x8*)(As + ((long)i*512 + t)*8) = av;
        }
    } else if constexpr (MODE == 1) {
        #pragma unroll
        for (int i = 0; i < NJ; i++) {
            bf16x8 av;
            #pragma unroll
            for (int j = 0; j < 8; j++)
                av[j] = (bf16)((float)ra[i][j] - fmaxf((float)rm[i][j], 0.f) * wbv[i]);
            *(bf16x8*)(As + ((long)i*512 + t)*8) = av;
        }
    }

    const int wm = wv >> 2, wn = wv & 3;
    f32x4 acc[2][5] = {};
    __syncthreads();

    #pragma unroll
    for (int s = 0; s < NSTEP; s++) {
        #pragma unroll
        for (int kh = 0; kh < 2; kh++) {
            const int kb = s*2 + kh;
            bf16x8 af[2], bq[5];
            #pragma unroll
            for (int m = 0; m < 2; m++)
                af[m] = *(const bf16x8*)(As + (((wm*2+m)*NKB + kb)*64 + lane)*8);
            #pragma unroll
            for (int n = 0; n < 5; n++)
                bq[n] = *(const bf16x8*)(Bs + ((wn*10 + n*2 + kh)*64 + lane)*8);
            #pragma unroll
            for (int m = 0; m < 2; m++)
                #pragma unroll
                for (int n = 0; n < 5; n++)
                    acc[m][n] = __builtin_amdgcn_mfma_f32_16x16x32_bf16(af[m], bq[n], acc[m][n], 0, 0, 0);
        }
        if (s + 1 < NSTEP) {
            __syncthreads();   // all reads of Bs done
            #pragma unroll
            for (int i = 0; i < 5; i++)
                gload16(Btg + (long)(s+1)*20480 + (long)(i*512 + t)*8,
                        Bs + ((long)i*512 + (t & ~63))*8);
            __syncthreads();   // DMA drained (compiler vmcnt(0) before barrier)
        }
    }

    const int kr = lane >> 4, lr = lane & 15;
    #pragma unroll
    for (int m = 0; m < 2; m++)
    #pragma unroll
    for (int n = 0; n < 5; n++)
    #pragma unroll
    for (int r = 0; r < 4; r++) {
        int row = row0 + wm*32 + m*16 + kr*4 + r;
        if (row >= M) continue;
        int col = wn*80 + n*16 + lr;
        float v = acc[m][n][r];
        if (add)  v += (float)add[(long)row*HP + col];
        if (bias) v += (col < H) ? bias[col] : 0.f;
        if (MODE == 2) v = fmaxf(v, 0.f);
        out[(long)row*HP + col] = (bf16)v;
    }
}

// ---------------- per-molecule weighted mean ----------------
__global__ void k_seg(const bf16* __restrict__ ah, const float* __restrict__ w_atoms,
                      const float* __restrict__ dop, float* __restrict__ out){
    int m = blockIdx.x; int t = threadIdx.x;
    __shared__ float ws_sum;
    float w = 0.f;
    if (t < APM) w = w_atoms[1 + m*APM + t];
    if (t < 64) {
        for (int o=32;o;o>>=1) w += __shfl_down(w, o);
        if (t==0) ws_sum = w;
    }
    __syncthreads();
    float scale = dop[m] / ws_sum;
    for (int h = t; h < H; h += 256) {
        float acc = 0.f;
        for (int j=0;j<APM;j++){
            int a = 1 + m*APM + j;
            acc += (float)ah[(long)a*HP + h] * w_atoms[a];
        }
        out[m*H + h] = acc * scale;
    }
}

__global__ void k_zero(float* __restrict__ out, int n){
    int i = blockIdx.x*256 + threadIdx.x;
    if (i < n) out[i] = 0.f;
}

extern "C" void kernel_launch(void* const* d_in, const int* in_sizes, int n_in,
                              void* d_out, int out_size, void* d_ws, size_t ws_size,
                              hipStream_t stream) {
    const float* f_atoms = (const float*)d_in[0];
    const float* f_bonds = (const float*)d_in[1];
    const float* w_atoms = (const float*)d_in[2];
    const float* w_bonds = (const float*)d_in[3];
    const float* dop     = (const float*)d_in[4];
    const float* W_i     = (const float*)d_in[5];
    const float* W_h     = (const float*)d_in[6];
    const float* W_o     = (const float*)d_in[7];
    const float* b_o     = (const float*)d_in[8];
    const int*   a2b     = (const int*)d_in[9];
    const int*   b2a     = (const int*)d_in[10];
    const int*   b2revb  = (const int*)d_in[11];
    float* out = (float*)d_out;
    (void)in_sizes; (void)n_in;

    const size_t R_BIG = ((size_t)NB*HP*2 + 255) & ~(size_t)255;   // 128 MB
    const size_t R_ATM = ((size_t)NA*HP*2 + 255) & ~(size_t)255;   //  64 MB
    const size_t R_WI  = ((size_t)HP*KIP*2 + 255) & ~(size_t)255;
    const size_t R_WH  = ((size_t)HP*HP*2 + 255) & ~(size_t)255;
    const size_t R_WO  = ((size_t)HP*KO*2 + 255) & ~(size_t)255;
    const size_t need  = 3*R_BIG + R_ATM + R_WI + R_WH + R_WO;

    if (ws_size < need) {
        k_zero<<<(out_size+255)/256, 256, 0, stream>>>(out, out_size);
        return;
    }

    char* ws = (char*)d_ws;
    bf16* inp  = (bf16*)ws;                    // GEMM1 out (raw), live to end of GEMM3
    bf16* msgA = (bf16*)(ws + R_BIG);          // GEMM2 out (raw); later aliased by cat
    bf16* msgB = (bf16*)(ws + 2*R_BIG);        // GEMM3 out (raw)
    bf16* amsg = (bf16*)(ws + 3*R_BIG);        // neighbor sums; later aliased by ah
    bf16* wit  = (bf16*)(ws + 3*R_BIG + R_ATM);
    bf16* wht  = (bf16*)((char*)wit + R_WI);
    bf16* wot  = (bf16*)((char*)wht + R_WH);
    bf16* cat  = msgA;                         // alias: msgA dead after GEMM3
    bf16* ah   = amsg;                         // alias: amsg dead after GEMM3

    k_prep<0, KIP><<<(HP*KIP+255)/256, 256, 0, stream>>>(W_i, wit);
    k_prep<1, HP ><<<(HP*HP +255)/256, 256, 0, stream>>>(W_h, wht);
    k_prep<2, KO ><<<(HP*KO +255)/256, 256, 0, stream>>>(W_o, wot);

    const int GB = (NB + BM - 1) / BM;   // 3126
    const int GA = (NA + BM - 1) / BM;   // 1563

    // inp = f_bonds @ W_i   (raw; relu applied on every read)
    k_gemm<0, KIP><<<GB, 512, 0, stream>>>(f_bonds, nullptr, nullptr, nullptr, nullptr,
                                           wit, NB, nullptr, nullptr, inp);
    // depth 1
    k_gather_amsg<<<(int)(((long)NA*40+255)/256), 256, 0, stream>>>(
        inp, a2b, w_bonds, amsg, HP, 0, 40);
    k_gemm<1, HP><<<GB, 512, 0, stream>>>(amsg, inp, b2a, b2revb, w_bonds,
                                          wht, NB, inp, nullptr, msgA);
    // depth 2
    k_gather_amsg<<<(int)(((long)NA*40+255)/256), 256, 0, stream>>>(
        msgA, a2b, w_bonds, amsg, HP, 0, 40);
    k_gemm<1, HP><<<GB, 512, 0, stream>>>(amsg, msgA, b2a, b2revb, w_bonds,
                                          wht, NB, inp, nullptr, msgB);
    // readout
    k_init_cat<<<(int)(((long)NA*18+255)/256), 256, 0, stream>>>(f_atoms, cat);
    k_gather_amsg<<<(int)(((long)NA*38+255)/256), 256, 0, stream>>>(
        msgB, a2b, w_bonds, cat, KO, AOFF, 38);
    k_gemm<2, KO><<<GA, 512, 0, stream>>>(cat, nullptr, nullptr, nullptr, nullptr,
                                          wot, NA, nullptr, b_o, ah);
    k_seg<<<NUM_MOLS, 256, 0, stream>>>(ah, w_atoms, dop, out);
}